// Round 1
// baseline (198.109 us; speedup 1.0000x reference)
//
#include <hip/hip_runtime.h>
#include <hip/hip_bf16.h>
#include <stdint.h>

// Problem constants
#define PB 2
#define PS 2048
#define PD 1024
#define PH 16
#define PHD 64
#define PM (PB*PS)   // 4096 rows

typedef _Float16 half8 __attribute__((ext_vector_type(8)));
typedef _Float16 half4v __attribute__((ext_vector_type(4)));
typedef __fp16   fp16x2 __attribute__((ext_vector_type(2)));
typedef float    f32x4 __attribute__((ext_vector_type(4)));

// async global->LDS, 16B per lane; LDS dst is wave-uniform base + lane*16.
// LESSON (R10): never feed MFMA fragments straight from global — the lane->
// address map is strided/scattered (16 cache lines per load) and VMEM dies.
// Stage coalesced into LDS; use XOR block swizzle (not padding) so the
// lane-linear DMA layout still gives conflict-free fragment reads.
__device__ __forceinline__ void ld_g2l_16(const void* g, void* l) {
  __builtin_amdgcn_global_load_lds(
      (const __attribute__((address_space(1))) unsigned int*)g,
      (__attribute__((address_space(3))) unsigned int*)l, 16, 0, 0);
}

// ---------------- fp32 -> fp16 convert (x), 8 elems/thread ----------------
__global__ void convert_f32_f16(const float* __restrict__ src,
                                _Float16* __restrict__ dst, int n8) {
  int i = blockIdx.x * blockDim.x + threadIdx.x;
  if (i >= n8) return;
  float4 f0 = reinterpret_cast<const float4*>(src)[2*i];
  float4 f1 = reinterpret_cast<const float4*>(src)[2*i+1];
  half8 o;
  o[0]=(_Float16)f0.x; o[1]=(_Float16)f0.y; o[2]=(_Float16)f0.z; o[3]=(_Float16)f0.w;
  o[4]=(_Float16)f1.x; o[5]=(_Float16)f1.y; o[6]=(_Float16)f1.z; o[7]=(_Float16)f1.w;
  reinterpret_cast<half8*>(dst)[i] = o;
}

// ---------------- fp32 -> fp16 convert (4 weights via blockIdx.y) ----------
__global__ void convert4_f32_f16(const float* __restrict__ w0, const float* __restrict__ w1,
                                 const float* __restrict__ w2, const float* __restrict__ w3,
                                 _Float16* __restrict__ dst, int n8) {
  int i = blockIdx.x * blockDim.x + threadIdx.x;
  if (i >= n8) return;
  int z = blockIdx.y;
  const float* src = (z==0)?w0:(z==1)?w1:(z==2)?w2:w3;
  float4 f0 = reinterpret_cast<const float4*>(src)[2*i];
  float4 f1 = reinterpret_cast<const float4*>(src)[2*i+1];
  half8 o;
  o[0]=(_Float16)f0.x; o[1]=(_Float16)f0.y; o[2]=(_Float16)f0.z; o[3]=(_Float16)f0.w;
  o[4]=(_Float16)f1.x; o[5]=(_Float16)f1.y; o[6]=(_Float16)f1.z; o[7]=(_Float16)f1.w;
  reinterpret_cast<half8*>(dst + (size_t)z*1024*1024)[i] = o;
}

// ------- fused projection GEMM: two weights per block, gelu fused ----------
// grid (M/128, N/128, 2), block 256 (4 waves, 2x2 wave tiling, 64x64/wave/weight)
// z=0: acc0 = x@Wq^T+bq, acc1 = x@Wg^T+bg -> qg = gelu(q*g) f16 [token][n]
// z=1: acc0 = x@Wk^T+bk -> k f16; acc1 = x@Wv^T+bv -> vT f16 [bh][64][2048]
// LDS XOR swizzle: row r stores 16B-block b at b^((r>>1)&3) -> frag reads
// land 2 lanes/4-bank window (free) instead of 4-way.
//
// R11: explicit 2-phase LDS double-buffer (T3-minimum). Grid is only 512
// blocks = 2 resident blocks/CU, so the old stage->barrier->MFMA->barrier
// structure had nothing to hide the per-K-step vmcnt(0) drain with
// (MfmaUtil 16%). Now: issue DMA for tile k+1 into buf^1 BEFORE computing
// tile k; ONE barrier per K-step (the barrier at end of step k-1 already
// guarantees no wave still reads buf^1). Load latency hides under MFMA.
__global__ __launch_bounds__(256, 2) void proj_fused(
    const _Float16* __restrict__ xh, const _Float16* __restrict__ wh,
    const float* __restrict__ bqp, const float* __restrict__ bkp,
    const float* __restrict__ bvp, const float* __restrict__ bgp,
    _Float16* __restrict__ qg, _Float16* __restrict__ kf,
    _Float16* __restrict__ vT)
{
  const int K = 1024;
  __shared__ _Float16 As[2][128*32];
  __shared__ _Float16 Bs0[2][128*32];
  __shared__ _Float16 Bs1[2][128*32];
  const int z = blockIdx.z;
  const size_t w0off = (size_t)(z==0 ? 0 : 1) * (1024*1024);  // q or k
  const size_t w1off = (size_t)(z==0 ? 3 : 2) * (1024*1024);  // g or v
  const float* bias0 = (z==0) ? bqp : bkp;
  const float* bias1 = (z==0) ? bgp : bvp;
  const int m0 = blockIdx.x * 128;
  const int n0 = blockIdx.y * 128;
  const int t = threadIdx.x;
  const int lane = t & 63;
  const int w = t >> 6;
  const int wr = w >> 1, wc = w & 1;
  const int lm = lane & 15, quad = lane >> 4;
  // staging swizzle: lane covers row lin>>2, stores LDS block lane&3; fetch
  // global block (lane&3)^key, key = (row>>1)&3 = (lane>>3)&3
  const int scb = (((lane&3) ^ ((lane>>3)&3)))*8;
  // frag-read unswizzle key (row = ..*16 + lm -> (row>>1)&3 = (lm>>1)&3)
  const int rblk = ((quad ^ ((lm>>1)&3)))*8;

  auto stage = [&](int buf, int k0) {
    #pragma unroll
    for (int c=0;c<2;c++) {
      int lin = c*256 + t;
      int row = lin >> 2;
      size_t ga = (size_t)(m0+row)*K + k0 + scb;
      size_t gb = (size_t)(n0+row)*K + k0 + scb;
      int lo8 = (c*256 + w*64)*8;     // wave-uniform LDS chunk base (in elems)
      ld_g2l_16(&xh[ga], &As[buf][lo8]);
      ld_g2l_16(&wh[w0off + gb], &Bs0[buf][lo8]);
      ld_g2l_16(&wh[w1off + gb], &Bs1[buf][lo8]);
    }
  };

  f32x4 acc0[4][4], acc1[4][4];
  #pragma unroll
  for (int i=0;i<4;i++)
    #pragma unroll
    for (int j=0;j<4;j++) {
      acc0[i][j] = (f32x4){0.f,0.f,0.f,0.f};
      acc1[i][j] = (f32x4){0.f,0.f,0.f,0.f};
    }

  // prologue: stage tile 0 into buffer 0. __syncthreads drains vmcnt(0).
  stage(0, 0);
  __syncthreads();

  for (int k0 = 0; k0 < K; k0 += 32) {
    const int cur = (k0 >> 5) & 1;
    // issue next tile's DMA FIRST — it completes while we run MFMAs below
    if (k0 + 32 < K) stage(cur ^ 1, k0 + 32);

    half8 ah[4];
    #pragma unroll
    for (int i=0;i<4;i++)
      ah[i] = *reinterpret_cast<const half8*>(&As[cur][(wr*64 + i*16 + lm)*32 + rblk]);
    #pragma unroll
    for (int j=0;j<4;j++) {
      const int bo = (wc*64 + j*16 + lm)*32 + rblk;
      half8 b0 = *reinterpret_cast<const half8*>(&Bs0[cur][bo]);
      half8 b1 = *reinterpret_cast<const half8*>(&Bs1[cur][bo]);
      #pragma unroll
      for (int i=0;i<4;i++) {
        acc0[i][j] = __builtin_amdgcn_mfma_f32_16x16x32_f16(ah[i], b0, acc0[i][j], 0,0,0);
        acc1[i][j] = __builtin_amdgcn_mfma_f32_16x16x32_f16(ah[i], b1, acc1[i][j], 0,0,0);
      }
    }
    // one barrier per K-step: compiler-inserted vmcnt(0)+lgkmcnt(0) drain
    // covers the next-tile DMA (issued ~full MFMA phase ago) and all waves'
    // reads of buf cur (so next iteration may overwrite buf cur).
    __syncthreads();
  }
  // epilogue. C layout: col=lane&15, row=quad*4+reg
  #pragma unroll
  for (int j=0;j<4;j++) {
    int n = n0 + wc*64 + j*16 + lm;
    float b0 = bias0[n];
    float b1 = bias1[n];
    #pragma unroll
    for (int i=0;i<4;i++) {
      int mb = m0 + wr*64 + i*16 + quad*4;
      #pragma unroll
      for (int r=0;r<4;r++) {
        int token = mb + r;
        float v0 = acc0[i][j][r] + b0;
        float v1 = acc1[i][j][r] + b1;
        if (z == 0) {
          float xx = v0 * v1;   // q*g
          float y = 0.5f * xx * (1.0f + erff(xx * 0.70710678118f));
          qg[(size_t)token*PD + n] = (_Float16)y;
        } else {
          kf[(size_t)token*PD + n] = (_Float16)v0;
          // V transposed: [bh][d=64][S=2048]
          int bb2 = token >> 11, ss = token & 2047;
          int hh = n >> 6, dd = n & 63;
          vT[((size_t)((bb2*16 + hh)*64 + dd))*2048 + ss] = (_Float16)v1;
        }
      }
    }
  }
}

// ---------------- flash attention v9 (LDS-staged, async DMA, swizzled) -----
// grid (S/64, B*H) = 1024 blocks, 4 waves. Wave w: 16 Q rows. K-tile = 64.
// K/V tiles staged via global_load_lds (no VGPR round-trip). Stride 64 with
// XOR block swizzle: row r's 16B-block b lives at block b^(r&7); frag reads
// use quad^(lm&7) -> 2 lanes/window, conflict-free. S^T trick: mfma(A=K,
// B=Q) -> lane holds 4 consecutive n of one Q row (m=lm); P stored packed
// b64, row-sum one scalar/lane. exp(s-8) constant shift (cancels in p/l,
// f16-safe to s<19.1), clamp 60000. 2 barriers/iter; P is per-wave LDS.
__global__ __launch_bounds__(256) void flash_attn(
    const _Float16* __restrict__ QG,   // [B*S][1024] f16
    const _Float16* __restrict__ Kp,   // [B*S][1024] f16
    const _Float16* __restrict__ VT,   // [bh][64][2048] f16
    float* __restrict__ out)           // [B*S][1024] fp32
{
  __shared__ _Float16 Ks[64*64];       // K tile [n][d], swizzled blocks
  __shared__ _Float16 Vts[64*64];      // V^T tile [d][n], swizzled blocks
  __shared__ _Float16 Pss[4][16*72];   // per-wave P [m][n], stride 72
  const int t = threadIdx.x;
  const int lane = t & 63, w = t >> 6;
  const int lm = lane & 15, quad = lane >> 4;
  const int bh = blockIdx.y;
  const int b = bh >> 4, h = bh & 15;
  const int qb = blockIdx.x * 64 + w * 16;   // this wave's first Q row
  const size_t kbase = (size_t)b * PS * PD + (size_t)h * PHD;
  const size_t vtb = (size_t)bh * 64 * 2048;

  // staging: lane covers row (w*8 + lane>>3), fetches global block
  // (lane&7)^(lane>>3) so LDS block (lane&7) holds swizzled data
  const int lrow = lane >> 3;
  const int lcb  = ((lane & 7) ^ lrow) * 8;
  // frag-read unswizzle: row&7 = lm&7; original blocks quad and quad+4
  const int kblk0 = ((quad     ^ (lm&7)))*8;
  const int kblk1 = (((quad+4) ^ (lm&7)))*8;

  // Q fragments: rows qb+lm, k = quad*8..+7 (+32); used as B operand
  half8 qf[2];
  {
    size_t qrow = kbase + (size_t)(qb + lm) * PD;
    qf[0] = *reinterpret_cast<const half8*>(&QG[qrow + quad*8]);
    qf[1] = *reinterpret_cast<const half8*>(&QG[qrow + 32 + quad*8]);
  }

  f32x4 o[4];
  #pragma unroll
  for (int dc=0;dc<4;dc++) o[dc] = (f32x4){0.f,0.f,0.f,0.f};
  float lsum = 0.f;   // partial row sum for row m = lm

  const _Float16* kgp = &Kp[kbase + (size_t)(w*8 + lrow)*PD + lcb];
  const _Float16* vgp = &VT[vtb + (size_t)(w*8 + lrow)*2048 + lcb];

  for (int kt = 0; kt < PS; kt += 64) {
    // async stage K rows kt..kt+63 and V^T cols kt..kt+63 (4 DMA calls/wave)
    ld_g2l_16(kgp + (size_t)kt*PD,      &Ks[(w*8)*64]);
    ld_g2l_16(kgp + (size_t)(kt+32)*PD, &Ks[(32 + w*8)*64]);
    ld_g2l_16(vgp + kt,                 &Vts[(w*8)*64]);
    ld_g2l_16(vgp + (size_t)32*2048 + kt, &Vts[(32 + w*8)*64]);
    __syncthreads();

    // S^T = K @ QG^T : lane holds (n = ns*16 + quad*4 + r, m = lm)
    f32x4 s[4];
    #pragma unroll
    for (int ns=0; ns<4; ns++) {
      const int rb = (ns*16 + lm)*64;
      half8 kf0 = *reinterpret_cast<const half8*>(&Ks[rb + kblk0]);
      half8 kf1 = *reinterpret_cast<const half8*>(&Ks[rb + kblk1]);
      f32x4 a = (f32x4){0.f,0.f,0.f,0.f};
      a = __builtin_amdgcn_mfma_f32_16x16x32_f16(kf0, qf[0], a, 0,0,0);
      a = __builtin_amdgcn_mfma_f32_16x16x32_f16(kf1, qf[1], a, 0,0,0);
      s[ns] = a;
    }

    // p = clamp(exp(s-8)); pack 4 consecutive-n f16 -> one b64 store per ns
    #pragma unroll
    for (int ns=0; ns<4; ns++) {
      float p0 = fminf(__expf(s[ns][0] - 8.0f), 60000.0f);
      float p1 = fminf(__expf(s[ns][1] - 8.0f), 60000.0f);
      float p2 = fminf(__expf(s[ns][2] - 8.0f), 60000.0f);
      float p3 = fminf(__expf(s[ns][3] - 8.0f), 60000.0f);
      lsum += (p0+p1) + (p2+p3);
      union { struct { fp16x2 a, b; } s2; half4v v; } u;
      u.s2.a = __builtin_amdgcn_cvt_pkrtz(p0, p1);
      u.s2.b = __builtin_amdgcn_cvt_pkrtz(p2, p3);
      *reinterpret_cast<half4v*>(&Pss[w][lm*72 + ns*16 + quad*4]) = u.v;
    }
    // per-wave LDS: compiler inserts lgkmcnt before readback; no barrier

    // O += P @ V (A = P[m][n] from LDS, B = V^T rows, swizzled blocks)
    half8 pa0 = *reinterpret_cast<const half8*>(&Pss[w][lm*72 + quad*8]);
    half8 pa1 = *reinterpret_cast<const half8*>(&Pss[w][lm*72 + 32 + quad*8]);
    #pragma unroll
    for (int dc=0;dc<4;dc++) {
      const int vb = (dc*16 + lm)*64;
      half8 vb0 = *reinterpret_cast<const half8*>(&Vts[vb + kblk0]);
      half8 vb1 = *reinterpret_cast<const half8*>(&Vts[vb + kblk1]);
      o[dc] = __builtin_amdgcn_mfma_f32_16x16x32_f16(pa0, vb0, o[dc], 0,0,0);
      o[dc] = __builtin_amdgcn_mfma_f32_16x16x32_f16(pa1, vb1, o[dc], 0,0,0);
    }
    __syncthreads();
  }

  // epilogue: reduce lsum across quads (same lm), fetch 1/l per written row
  float l = lsum;
  l += __shfl_xor(l, 16);
  l += __shfl_xor(l, 32);
  float inv = 1.0f / l;          // valid for row m = lm on every lane
  #pragma unroll
  for (int r=0;r<4;r++) {
    int m = quad*4 + r;
    float invr = __shfl(inv, m); // pull from lane m (quad 0, lm=m)
    int row = qb + m;
    size_t ob = kbase + (size_t)row * PD;
    #pragma unroll
    for (int dc=0;dc<4;dc++) {
      out[ob + dc*16 + lm] = o[dc][r] * invr;
    }
  }
}

extern "C" void kernel_launch(void* const* d_in, const int* in_sizes, int n_in,
                              void* d_out, int out_size, void* d_ws, size_t ws_size,
                              hipStream_t stream) {
  const float* x  = (const float*)d_in[0];
  const float* Wq = (const float*)d_in[1];
  const float* bq = (const float*)d_in[2];
  const float* Wk = (const float*)d_in[3];
  const float* bk = (const float*)d_in[4];
  const float* Wv = (const float*)d_in[5];
  const float* bv = (const float*)d_in[6];
  const float* Wg = (const float*)d_in[7];
  const float* bg = (const float*)d_in[8];
  float* out = (float*)d_out;

  char* ws = (char*)d_ws;
  const size_t MB = 1u << 20;
  // layout (MiB): 0 xh(8), 8 wh(8), 16 qg(8), 24 kf(8), 32 vT(8) = 40 MiB
  _Float16* xh = (_Float16*)(ws + 0*MB);
  _Float16* wh = (_Float16*)(ws + 8*MB);
  _Float16* qg = (_Float16*)(ws + 16*MB);
  _Float16* kf = (_Float16*)(ws + 24*MB);
  _Float16* vT = (_Float16*)(ws + 32*MB);

  const int NW = 1024*1024;          // elems per weight
  const int NX = PM*PD;              // 4,194,304 elems in x

  convert_f32_f16<<<NX/8/256, 256, 0, stream>>>(x, xh, NX/8);
  convert4_f32_f16<<<dim3(NW/8/256, 4), 256, 0, stream>>>(Wq, Wk, Wv, Wg, wh, NW/8);

  proj_fused<<<dim3(PM/128, PD/128, 2), 256, 0, stream>>>(
      xh, wh, bq, bk, bv, bg, qg, kf, vT);

  flash_attn<<<dim3(PS/64, PB*PH), 256, 0, stream>>>(qg, kf, vT, out);
}

// Round 2
// 196.749 us; speedup vs baseline: 1.0069x; 1.0069x over previous
//
#include <hip/hip_runtime.h>
#include <hip/hip_bf16.h>
#include <stdint.h>

// Problem constants
#define PB 2
#define PS 2048
#define PD 1024
#define PH 16
#define PHD 64
#define PM (PB*PS)   // 4096 rows

typedef _Float16 half8 __attribute__((ext_vector_type(8)));
typedef _Float16 half4v __attribute__((ext_vector_type(4)));
typedef __fp16   fp16x2 __attribute__((ext_vector_type(2)));
typedef float    f32x4 __attribute__((ext_vector_type(4)));

// async global->LDS, 16B per lane; LDS dst is wave-uniform base + lane*16.
// LESSON (R10): never feed MFMA fragments straight from global — the lane->
// address map is strided/scattered (16 cache lines per load) and VMEM dies.
// Stage coalesced into LDS; use XOR block swizzle (not padding) so the
// lane-linear DMA layout still gives conflict-free fragment reads.
__device__ __forceinline__ void ld_g2l_16(const void* g, void* l) {
  __builtin_amdgcn_global_load_lds(
      (const __attribute__((address_space(1))) unsigned int*)g,
      (__attribute__((address_space(3))) unsigned int*)l, 16, 0, 0);
}

// ---------------- fp32 -> fp16 convert (x), 8 elems/thread ----------------
__global__ void convert_f32_f16(const float* __restrict__ src,
                                _Float16* __restrict__ dst, int n8) {
  int i = blockIdx.x * blockDim.x + threadIdx.x;
  if (i >= n8) return;
  float4 f0 = reinterpret_cast<const float4*>(src)[2*i];
  float4 f1 = reinterpret_cast<const float4*>(src)[2*i+1];
  half8 o;
  o[0]=(_Float16)f0.x; o[1]=(_Float16)f0.y; o[2]=(_Float16)f0.z; o[3]=(_Float16)f0.w;
  o[4]=(_Float16)f1.x; o[5]=(_Float16)f1.y; o[6]=(_Float16)f1.z; o[7]=(_Float16)f1.w;
  reinterpret_cast<half8*>(dst)[i] = o;
}

// ---------------- fp32 -> fp16 convert (4 weights via blockIdx.y) ----------
__global__ void convert4_f32_f16(const float* __restrict__ w0, const float* __restrict__ w1,
                                 const float* __restrict__ w2, const float* __restrict__ w3,
                                 _Float16* __restrict__ dst, int n8) {
  int i = blockIdx.x * blockDim.x + threadIdx.x;
  if (i >= n8) return;
  int z = blockIdx.y;
  const float* src = (z==0)?w0:(z==1)?w1:(z==2)?w2:w3;
  float4 f0 = reinterpret_cast<const float4*>(src)[2*i];
  float4 f1 = reinterpret_cast<const float4*>(src)[2*i+1];
  half8 o;
  o[0]=(_Float16)f0.x; o[1]=(_Float16)f0.y; o[2]=(_Float16)f0.z; o[3]=(_Float16)f0.w;
  o[4]=(_Float16)f1.x; o[5]=(_Float16)f1.y; o[6]=(_Float16)f1.z; o[7]=(_Float16)f1.w;
  reinterpret_cast<half8*>(dst + (size_t)z*1024*1024)[i] = o;
}

// ------- fused projection GEMM: two weights per block, gelu fused ----------
// grid (M/128, N/128, 2), block 256 (4 waves, 2x2 wave tiling, 64x64/wave/weight)
// z=0: acc0 = x@Wq^T+bq, acc1 = x@Wg^T+bg -> qg = gelu(q*g)*log2e f16
// z=1: acc0 = x@Wk^T+bk -> k f16; acc1 = x@Wv^T+bv -> vT f16 [bh][64][2048]
// LDS XOR swizzle: row r stores 16B-block b at b^((r>>1)&3) -> frag reads
// land 2 lanes/4-bank window (free) instead of 4-way.
//
// R11: explicit 2-phase LDS double-buffer (T3-minimum); dropped proj out of
// the top-5 dispatches. R12: qg is pre-scaled by log2(e) so flash_attn can
// use raw v_exp_f32 (2^x) with the -8 shift folded into the MFMA C-init.
__global__ __launch_bounds__(256, 2) void proj_fused(
    const _Float16* __restrict__ xh, const _Float16* __restrict__ wh,
    const float* __restrict__ bqp, const float* __restrict__ bkp,
    const float* __restrict__ bvp, const float* __restrict__ bgp,
    _Float16* __restrict__ qg, _Float16* __restrict__ kf,
    _Float16* __restrict__ vT)
{
  const int K = 1024;
  __shared__ _Float16 As[2][128*32];
  __shared__ _Float16 Bs0[2][128*32];
  __shared__ _Float16 Bs1[2][128*32];
  const int z = blockIdx.z;
  const size_t w0off = (size_t)(z==0 ? 0 : 1) * (1024*1024);  // q or k
  const size_t w1off = (size_t)(z==0 ? 3 : 2) * (1024*1024);  // g or v
  const float* bias0 = (z==0) ? bqp : bkp;
  const float* bias1 = (z==0) ? bgp : bvp;
  const int m0 = blockIdx.x * 128;
  const int n0 = blockIdx.y * 128;
  const int t = threadIdx.x;
  const int lane = t & 63;
  const int w = t >> 6;
  const int wr = w >> 1, wc = w & 1;
  const int lm = lane & 15, quad = lane >> 4;
  // staging swizzle: lane covers row lin>>2, stores LDS block lane&3; fetch
  // global block (lane&3)^key, key = (row>>1)&3 = (lane>>3)&3
  const int scb = (((lane&3) ^ ((lane>>3)&3)))*8;
  // frag-read unswizzle key (row = ..*16 + lm -> (row>>1)&3 = (lm>>1)&3)
  const int rblk = ((quad ^ ((lm>>1)&3)))*8;

  auto stage = [&](int buf, int k0) {
    #pragma unroll
    for (int c=0;c<2;c++) {
      int lin = c*256 + t;
      int row = lin >> 2;
      size_t ga = (size_t)(m0+row)*K + k0 + scb;
      size_t gb = (size_t)(n0+row)*K + k0 + scb;
      int lo8 = (c*256 + w*64)*8;     // wave-uniform LDS chunk base (in elems)
      ld_g2l_16(&xh[ga], &As[buf][lo8]);
      ld_g2l_16(&wh[w0off + gb], &Bs0[buf][lo8]);
      ld_g2l_16(&wh[w1off + gb], &Bs1[buf][lo8]);
    }
  };

  f32x4 acc0[4][4], acc1[4][4];
  #pragma unroll
  for (int i=0;i<4;i++)
    #pragma unroll
    for (int j=0;j<4;j++) {
      acc0[i][j] = (f32x4){0.f,0.f,0.f,0.f};
      acc1[i][j] = (f32x4){0.f,0.f,0.f,0.f};
    }

  // prologue: stage tile 0 into buffer 0. __syncthreads drains vmcnt(0).
  stage(0, 0);
  __syncthreads();

  for (int k0 = 0; k0 < K; k0 += 32) {
    const int cur = (k0 >> 5) & 1;
    // issue next tile's DMA FIRST — it completes while we run MFMAs below
    if (k0 + 32 < K) stage(cur ^ 1, k0 + 32);

    half8 ah[4];
    #pragma unroll
    for (int i=0;i<4;i++)
      ah[i] = *reinterpret_cast<const half8*>(&As[cur][(wr*64 + i*16 + lm)*32 + rblk]);
    #pragma unroll
    for (int j=0;j<4;j++) {
      const int bo = (wc*64 + j*16 + lm)*32 + rblk;
      half8 b0 = *reinterpret_cast<const half8*>(&Bs0[cur][bo]);
      half8 b1 = *reinterpret_cast<const half8*>(&Bs1[cur][bo]);
      #pragma unroll
      for (int i=0;i<4;i++) {
        acc0[i][j] = __builtin_amdgcn_mfma_f32_16x16x32_f16(ah[i], b0, acc0[i][j], 0,0,0);
        acc1[i][j] = __builtin_amdgcn_mfma_f32_16x16x32_f16(ah[i], b1, acc1[i][j], 0,0,0);
      }
    }
    // one barrier per K-step: compiler-inserted vmcnt(0)+lgkmcnt(0) drain
    // covers the next-tile DMA (issued ~full MFMA phase ago) and all waves'
    // reads of buf cur (so next iteration may overwrite buf cur).
    __syncthreads();
  }
  // epilogue. C layout: col=lane&15, row=quad*4+reg
  #pragma unroll
  for (int j=0;j<4;j++) {
    int n = n0 + wc*64 + j*16 + lm;
    float b0 = bias0[n];
    float b1 = bias1[n];
    #pragma unroll
    for (int i=0;i<4;i++) {
      int mb = m0 + wr*64 + i*16 + quad*4;
      #pragma unroll
      for (int r=0;r<4;r++) {
        int token = mb + r;
        float v0 = acc0[i][j][r] + b0;
        float v1 = acc1[i][j][r] + b1;
        if (z == 0) {
          float xx = v0 * v1;   // q*g
          float y = 0.5f * xx * (1.0f + erff(xx * 0.70710678118f));
          // pre-scale by log2(e): flash computes p = 2^(s') = e^s exactly;
          // error propagation identical (d2^x = ln2*2^x cancels the *log2e)
          qg[(size_t)token*PD + n] = (_Float16)(y * 1.44269504f);
        } else {
          kf[(size_t)token*PD + n] = (_Float16)v0;
          // V transposed: [bh][d=64][S=2048]
          int bb2 = token >> 11, ss = token & 2047;
          int hh = n >> 6, dd = n & 63;
          vT[((size_t)((bb2*16 + hh)*64 + dd))*2048 + ss] = (_Float16)v1;
        }
      }
    }
  }
}

// ---------------- flash attention v10 (pipelined, lean softmax) ------------
// grid (S/64, B*H) = 1024 blocks, 4 waves. Wave w: 16 Q rows. K-tile = 64.
// R12 changes vs v9:
//  * K double-buffered via global_load_lds (Ks[2]); V pipelined via T14
//    reg-staging (global->float4 regs at loop top, regs->LDS after the
//    barrier retiring PV's reads of V(t)). LDS 33.8KB -> still 4 blocks/CU.
//    Both barriers/iter are now cheap: the vmcnt drain lands a full compute
//    phase after issue (v9 exposed full K/V fetch latency every tile).
//  * softmax: qg pre-scaled by log2e + QK MFMA C-init = -8*log2e, so
//    p = exp2(s) directly (v_exp_f32): kills the per-element sub and mul.
//  * s_setprio(1) around MFMA clusters (T5).
// S^T trick unchanged: mfma(A=K, B=Q) -> lane holds 4 consecutive n of one
// Q row (m=lm); P packed b64 to per-wave LDS; clamp 60000 (f16-safe).
__global__ __launch_bounds__(256) void flash_attn(
    const _Float16* __restrict__ QG,   // [B*S][1024] f16  (pre-scaled log2e)
    const _Float16* __restrict__ Kp,   // [B*S][1024] f16
    const _Float16* __restrict__ VT,   // [bh][64][2048] f16
    float* __restrict__ out)           // [B*S][1024] fp32
{
  __shared__ _Float16 Ks[2][64*64];    // K tile [n][d], swizzled, dbuf (16KB)
  __shared__ _Float16 Vts[64*64];      // V^T tile [d][n], swizzled (8KB)
  __shared__ _Float16 Pss[4][16*72];   // per-wave P [m][n], stride 72 (9KB)
  const int t = threadIdx.x;
  const int lane = t & 63, w = t >> 6;
  const int lm = lane & 15, quad = lane >> 4;
  const int bh = blockIdx.y;
  const int b = bh >> 4, h = bh & 15;
  const int qb = blockIdx.x * 64 + w * 16;   // this wave's first Q row
  const size_t kbase = (size_t)b * PS * PD + (size_t)h * PHD;
  const size_t vtb = (size_t)bh * 64 * 2048;

  // staging: lane covers row (w*8 + lane>>3), fetches global block
  // (lane&7)^(lane>>3) so LDS block (lane&7) holds swizzled data
  const int lrow = lane >> 3;
  const int lcb  = ((lane & 7) ^ lrow) * 8;
  // frag-read unswizzle: row&7 = lm&7; original blocks quad and quad+4
  const int kblk0 = ((quad     ^ (lm&7)))*8;
  const int kblk1 = (((quad+4) ^ (lm&7)))*8;

  // Q fragments: rows qb+lm, k = quad*8..+7 (+32); used as B operand
  half8 qf[2];
  {
    size_t qrow = kbase + (size_t)(qb + lm) * PD;
    qf[0] = *reinterpret_cast<const half8*>(&QG[qrow + quad*8]);
    qf[1] = *reinterpret_cast<const half8*>(&QG[qrow + 32 + quad*8]);
  }

  f32x4 o[4];
  #pragma unroll
  for (int dc=0;dc<4;dc++) o[dc] = (f32x4){0.f,0.f,0.f,0.f};
  float lsum = 0.f;   // partial row sum for row m = lm

  const _Float16* kgp = &Kp[kbase + (size_t)(w*8 + lrow)*PD + lcb];
  const _Float16* vgp = &VT[vtb + (size_t)(w*8 + lrow)*2048 + lcb];
  // this lane's LDS slots for the manual V write (same net layout as DMA:
  // LDS block lane&7 of row w*8+lrow holds global block (lane&7)^lrow)
  _Float16* vdst0 = &Vts[((w*8 + lrow)*8 + (lane & 7))*8];
  _Float16* vdst1 = vdst0 + 32*64;

  // QK accumulator C-init: -8*log2(e) => p = 2^s = e^(q.k - 8)
  const f32x4 sinit = {-11.54156036f, -11.54156036f, -11.54156036f, -11.54156036f};

  // prologue: stage tile 0 (K and V both via DMA), then one drain barrier
  ld_g2l_16(kgp,                        &Ks[0][(w*8)*64]);
  ld_g2l_16(kgp + (size_t)32*PD,        &Ks[0][(32 + w*8)*64]);
  ld_g2l_16(vgp,                        &Vts[(w*8)*64]);
  ld_g2l_16(vgp + (size_t)32*2048,      &Vts[(32 + w*8)*64]);
  __syncthreads();

  for (int kt = 0; kt < PS; kt += 64) {
    const int buf = (kt >> 6) & 1;
    const bool nx = (kt + 64) < PS;
    float4 vr0, vr1;
    if (nx) {
      // prefetch next K tile straight to LDS (buf^1 retired one full
      // barrier-pair ago) and next V tile to registers
      ld_g2l_16(kgp + (size_t)(kt+64)*PD, &Ks[buf^1][(w*8)*64]);
      ld_g2l_16(kgp + (size_t)(kt+96)*PD, &Ks[buf^1][(32 + w*8)*64]);
      vr0 = *reinterpret_cast<const float4*>(vgp + kt + 64);
      vr1 = *reinterpret_cast<const float4*>(vgp + (size_t)32*2048 + kt + 64);
    }

    // S^T = K @ QG^T : lane holds (n = ns*16 + quad*4 + r, m = lm)
    f32x4 s[4];
    __builtin_amdgcn_s_setprio(1);
    #pragma unroll
    for (int ns=0; ns<4; ns++) {
      const int rb = (ns*16 + lm)*64;
      half8 kf0 = *reinterpret_cast<const half8*>(&Ks[buf][rb + kblk0]);
      half8 kf1 = *reinterpret_cast<const half8*>(&Ks[buf][rb + kblk1]);
      f32x4 a = sinit;
      a = __builtin_amdgcn_mfma_f32_16x16x32_f16(kf0, qf[0], a, 0,0,0);
      a = __builtin_amdgcn_mfma_f32_16x16x32_f16(kf1, qf[1], a, 0,0,0);
      s[ns] = a;
    }
    __builtin_amdgcn_s_setprio(0);

    // p = clamp(2^s); pack 4 consecutive-n f16 -> one b64 store per ns
    #pragma unroll
    for (int ns=0; ns<4; ns++) {
      float p0 = fminf(__builtin_amdgcn_exp2f(s[ns][0]), 60000.0f);
      float p1 = fminf(__builtin_amdgcn_exp2f(s[ns][1]), 60000.0f);
      float p2 = fminf(__builtin_amdgcn_exp2f(s[ns][2]), 60000.0f);
      float p3 = fminf(__builtin_amdgcn_exp2f(s[ns][3]), 60000.0f);
      lsum += (p0+p1) + (p2+p3);
      union { struct { fp16x2 a, b; } s2; half4v v; } u;
      u.s2.a = __builtin_amdgcn_cvt_pkrtz(p0, p1);
      u.s2.b = __builtin_amdgcn_cvt_pkrtz(p2, p3);
      *reinterpret_cast<half4v*>(&Pss[w][lm*72 + ns*16 + quad*4]) = u.v;
    }
    // per-wave LDS: compiler inserts lgkmcnt before readback; no barrier

    // O += P @ V (A = P[m][n] from LDS, B = V^T rows, swizzled blocks)
    half8 pa0 = *reinterpret_cast<const half8*>(&Pss[w][lm*72 + quad*8]);
    half8 pa1 = *reinterpret_cast<const half8*>(&Pss[w][lm*72 + 32 + quad*8]);
    __builtin_amdgcn_s_setprio(1);
    #pragma unroll
    for (int dc=0;dc<4;dc++) {
      const int vb = (dc*16 + lm)*64;
      half8 vb0 = *reinterpret_cast<const half8*>(&Vts[vb + kblk0]);
      half8 vb1 = *reinterpret_cast<const half8*>(&Vts[vb + kblk1]);
      o[dc] = __builtin_amdgcn_mfma_f32_16x16x32_f16(pa0, vb0, o[dc], 0,0,0);
      o[dc] = __builtin_amdgcn_mfma_f32_16x16x32_f16(pa1, vb1, o[dc], 0,0,0);
    }
    __builtin_amdgcn_s_setprio(0);

    // barrier 1: all waves done reading Vts(t) + drains this wave's K-DMA
    // (issued a full compute phase ago) and vr loads
    __syncthreads();
    if (nx) {
      *reinterpret_cast<float4*>(vdst0) = vr0;
      *reinterpret_cast<float4*>(vdst1) = vr1;
    }
    // barrier 2: Vts(t+1) visible to all waves (orders the cheap ds_writes)
    __syncthreads();
  }

  // epilogue: reduce lsum across quads (same lm), fetch 1/l per written row
  float l = lsum;
  l += __shfl_xor(l, 16);
  l += __shfl_xor(l, 32);
  float inv = 1.0f / l;          // valid for row m = lm on every lane
  #pragma unroll
  for (int r=0;r<4;r++) {
    int m = quad*4 + r;
    float invr = __shfl(inv, m); // pull from lane m (quad 0, lm=m)
    int row = qb + m;
    size_t ob = kbase + (size_t)row * PD;
    #pragma unroll
    for (int dc=0;dc<4;dc++) {
      out[ob + dc*16 + lm] = o[dc][r] * invr;
    }
  }
}

extern "C" void kernel_launch(void* const* d_in, const int* in_sizes, int n_in,
                              void* d_out, int out_size, void* d_ws, size_t ws_size,
                              hipStream_t stream) {
  const float* x  = (const float*)d_in[0];
  const float* Wq = (const float*)d_in[1];
  const float* bq = (const float*)d_in[2];
  const float* Wk = (const float*)d_in[3];
  const float* bk = (const float*)d_in[4];
  const float* Wv = (const float*)d_in[5];
  const float* bv = (const float*)d_in[6];
  const float* Wg = (const float*)d_in[7];
  const float* bg = (const float*)d_in[8];
  float* out = (float*)d_out;

  char* ws = (char*)d_ws;
  const size_t MB = 1u << 20;
  // layout (MiB): 0 xh(8), 8 wh(8), 16 qg(8), 24 kf(8), 32 vT(8) = 40 MiB
  _Float16* xh = (_Float16*)(ws + 0*MB);
  _Float16* wh = (_Float16*)(ws + 8*MB);
  _Float16* qg = (_Float16*)(ws + 16*MB);
  _Float16* kf = (_Float16*)(ws + 24*MB);
  _Float16* vT = (_Float16*)(ws + 32*MB);

  const int NW = 1024*1024;          // elems per weight
  const int NX = PM*PD;              // 4,194,304 elems in x

  convert_f32_f16<<<NX/8/256, 256, 0, stream>>>(x, xh, NX/8);
  convert4_f32_f16<<<dim3(NW/8/256, 4), 256, 0, stream>>>(Wq, Wk, Wv, Wg, wh, NW/8);

  proj_fused<<<dim3(PM/128, PD/128, 2), 256, 0, stream>>>(
      xh, wh, bq, bk, bv, bg, qg, kf, vT);

  flash_attn<<<dim3(PS/64, PB*PH), 256, 0, stream>>>(qg, kf, vT, out);
}

// Round 3
// 194.835 us; speedup vs baseline: 1.0168x; 1.0098x over previous
//
#include <hip/hip_runtime.h>
#include <hip/hip_bf16.h>
#include <stdint.h>

// Problem constants
#define PB 2
#define PS 2048
#define PD 1024
#define PH 16
#define PHD 64
#define PM (PB*PS)   // 4096 rows

typedef _Float16 half8 __attribute__((ext_vector_type(8)));
typedef _Float16 half4v __attribute__((ext_vector_type(4)));
typedef __fp16   fp16x2 __attribute__((ext_vector_type(2)));
typedef float    f32x4 __attribute__((ext_vector_type(4)));

// async global->LDS, 16B per lane; LDS dst is wave-uniform base + lane*16.
// LESSON (R10): never feed MFMA fragments straight from global — the lane->
// address map is strided/scattered (16 cache lines per load) and VMEM dies.
// Stage coalesced into LDS; use XOR block swizzle (not padding) so the
// lane-linear DMA layout still gives conflict-free fragment reads.
__device__ __forceinline__ void ld_g2l_16(const void* g, void* l) {
  __builtin_amdgcn_global_load_lds(
      (const __attribute__((address_space(1))) unsigned int*)g,
      (__attribute__((address_space(3))) unsigned int*)l, 16, 0, 0);
}

// ------------- fp32 -> fp16 convert, x and all 4 weights, one launch ------
// y=0: x (4.19M elems = 524288 half8); y=1: four 1M-elem weights -> wh slots
// q(0), k(1), v(2), g(3).
__global__ void convert_all(const float* __restrict__ x,
                            const float* __restrict__ w0, const float* __restrict__ w1,
                            const float* __restrict__ w2, const float* __restrict__ w3,
                            _Float16* __restrict__ xh, _Float16* __restrict__ wh) {
  int i = blockIdx.x * blockDim.x + threadIdx.x;
  const float* src;
  _Float16* dst;
  int idx;
  if (blockIdx.y == 0) {
    src = x; dst = xh; idx = i;
  } else {
    int wsel = i >> 17;            // 131072 half8 per weight
    idx = i & 131071;
    src = (wsel==0)?w0:(wsel==1)?w1:(wsel==2)?w2:w3;
    dst = wh + (size_t)wsel * 1048576;
  }
  float4 f0 = reinterpret_cast<const float4*>(src)[2*idx];
  float4 f1 = reinterpret_cast<const float4*>(src)[2*idx+1];
  half8 o;
  o[0]=(_Float16)f0.x; o[1]=(_Float16)f0.y; o[2]=(_Float16)f0.z; o[3]=(_Float16)f0.w;
  o[4]=(_Float16)f1.x; o[5]=(_Float16)f1.y; o[6]=(_Float16)f1.z; o[7]=(_Float16)f1.w;
  reinterpret_cast<half8*>(dst)[idx] = o;
}

// ------------------ projection GEMM: one weight per block ------------------
// R13: uniform 4-way split (z: 0=q,1=g,2=k,3=v), 128x128 tile, 1024 blocks.
// R12's dual-weight blocks used ~220 unified regs (92 VGPR + 128 AGPR acc)
// -> hard 2 waves/SIMD cap, and the 512-block grid gave 2 blocks/CU: the
// double-buffer had nothing to overlap with (MfmaUtil stuck ~17%). Single
// acc[4][4] (~115 regs) + 32KB LDS + __launch_bounds__(256,3) -> 3
// blocks/CU resident, m97-regime wave-level latency hiding.
// gelu(q*g) moved to flash's Q-load (q,g stored raw f16).
// z==3 (v): epilogue LDS-transpose (reuse staging LDS) -> coalesced half8
// vT stores. The old per-element scatter fanned each store-instr to 64
// cache lines (WRITE_SIZE 48MB vs 24 ideal).
// LDS XOR swizzle unchanged: row r stores 16B-block b at b^((r>>1)&3).
__global__ __launch_bounds__(256, 3) void proj_gemm(
    const _Float16* __restrict__ xh, const _Float16* __restrict__ wh,
    const float* __restrict__ bqp, const float* __restrict__ bgp,
    const float* __restrict__ bkp, const float* __restrict__ bvp,
    _Float16* __restrict__ qf, _Float16* __restrict__ gf,
    _Float16* __restrict__ kf, _Float16* __restrict__ vT)
{
  const int K = 1024;
  __shared__ _Float16 Sm[16384];   // 32KB: A dbuf [0:8192), B dbuf [8192:16384)
  const int z = blockIdx.z;
  const int wslot = (z==0)?0:(z==1)?3:(z==2)?1:2;   // wh order q,k,v,g
  const size_t woff = (size_t)wslot * (1024*1024);
  const float* bias = (z==0)?bqp:(z==1)?bgp:(z==2)?bkp:bvp;
  _Float16* outp = (z==0)?qf:(z==1)?gf:kf;          // z==3 handled separately
  const int m0 = blockIdx.x * 128;
  const int n0 = blockIdx.y * 128;
  const int t = threadIdx.x;
  const int lane = t & 63;
  const int w = t >> 6;
  const int wr = w >> 1, wc = w & 1;
  const int lm = lane & 15, quad = lane >> 4;
  // staging swizzle: lane covers row lin>>2, stores LDS block lane&3; fetch
  // global block (lane&3)^key, key = (row>>1)&3 = (lane>>3)&3
  const int scb = (((lane&3) ^ ((lane>>3)&3)))*8;
  // frag-read unswizzle key (row = ..*16 + lm -> (row>>1)&3 = (lm>>1)&3)
  const int rblk = ((quad ^ ((lm>>1)&3)))*8;

  auto stage = [&](int buf, int k0) {
    #pragma unroll
    for (int c=0;c<2;c++) {
      int lin = c*256 + t;
      int row = lin >> 2;
      size_t ga = (size_t)(m0+row)*K + k0 + scb;
      size_t gb = (size_t)(n0+row)*K + k0 + scb;
      int lo8 = (c*256 + w*64)*8;     // wave-uniform LDS chunk base (elems)
      ld_g2l_16(&xh[ga],        &Sm[buf*4096 + lo8]);
      ld_g2l_16(&wh[woff + gb], &Sm[8192 + buf*4096 + lo8]);
    }
  };

  f32x4 acc[4][4];
  #pragma unroll
  for (int i=0;i<4;i++)
    #pragma unroll
    for (int j=0;j<4;j++) acc[i][j] = (f32x4){0.f,0.f,0.f,0.f};

  stage(0, 0);
  __syncthreads();

  for (int k0 = 0; k0 < K; k0 += 32) {
    const int cur = (k0 >> 5) & 1;
    if (k0 + 32 < K) stage(cur ^ 1, k0 + 32);   // prefetch under MFMAs

    half8 ah[4];
    #pragma unroll
    for (int i=0;i<4;i++)
      ah[i] = *reinterpret_cast<const half8*>(&Sm[cur*4096 + (wr*64 + i*16 + lm)*32 + rblk]);
    #pragma unroll
    for (int j=0;j<4;j++) {
      half8 b = *reinterpret_cast<const half8*>(&Sm[8192 + cur*4096 + (wc*64 + j*16 + lm)*32 + rblk]);
      #pragma unroll
      for (int i=0;i<4;i++)
        acc[i][j] = __builtin_amdgcn_mfma_f32_16x16x32_f16(ah[i], b, acc[i][j], 0,0,0);
    }
    // single barrier/K-step: drains next-tile DMA (issued a full MFMA phase
    // ago) and retires all waves' reads of buf cur.
    __syncthreads();
  }

  // epilogue. C layout: col=lane&15, row=quad*4+reg
  if (z < 3) {
    #pragma unroll
    for (int j=0;j<4;j++) {
      int n = n0 + wc*64 + j*16 + lm;
      float bn = bias[n];
      #pragma unroll
      for (int i=0;i<4;i++) {
        int mb = m0 + wr*64 + i*16 + quad*4;
        #pragma unroll
        for (int r=0;r<4;r++)
          outp[(size_t)(mb+r)*PD + n] = (_Float16)(acc[i][j][r] + bn);
      }
    }
  } else {
    // v: transpose 128(token) x 128(n) tile through LDS, store coalesced.
    // Sm row = n_local (128 tokens/row); token-chunk c (8 elems) stored at
    // chunk position c ^ (n_local&15)  -> both sides swizzled, banks spread.
    #pragma unroll
    for (int j=0;j<4;j++) {
      int nl = wc*64 + j*16 + lm;
      float bn = bias[n0 + nl];
      #pragma unroll
      for (int i=0;i<4;i++) {
        int tb = wr*64 + i*16 + quad*4;   // token base, 8B-aligned in chunk
        half4v pv;
        #pragma unroll
        for (int r=0;r<4;r++) pv[r] = (_Float16)(acc[i][j][r] + bn);
        int sw = (tb >> 3) ^ (nl & 15);
        *reinterpret_cast<half4v*>(&Sm[nl*128 + sw*8 + (tb & 7)]) = pv;
      }
    }
    __syncthreads();
    // copy out: thread t -> vT row nl2 = t>>1, token-half (t&1)*64.
    // vT[bh][d][s]: contiguous along s -> half8 stores, fully coalesced.
    const int nl2 = t >> 1, co = (t & 1) * 8;
    const int hh = (n0 + nl2) >> 6, dd = (n0 + nl2) & 63;
    const int bb2 = m0 >> 11;
    const size_t vbase = ((size_t)((bb2*16 + hh)*64 + dd))*2048 + (m0 & 2047);
    #pragma unroll
    for (int c=0;c<8;c++) {
      int cc = co + c;
      half8 vv = *reinterpret_cast<const half8*>(&Sm[nl2*128 + ((cc ^ (nl2&15))<<3)]);
      *reinterpret_cast<half8*>(&vT[vbase + cc*8]) = vv;
    }
  }
}

// ---------------- flash attention v11 (pipelined, lean softmax) ------------
// grid (S/64, B*H) = 1024 blocks, 4 waves. Wave w: 16 Q rows. K-tile = 64.
// R13: Q-fragment load now computes qg = gelu(q*g)*log2e from the split
// q/g buffers (once per block, ~16 elems/lane — proj no longer fuses it).
// K double-buffered via global_load_lds; V pipelined via reg-staging.
// softmax: p = exp2(s) with C-init = -8*log2e. setprio around MFMA clusters.
__global__ __launch_bounds__(256) void flash_attn(
    const _Float16* __restrict__ Qf,   // [B*S][1024] f16 (raw q)
    const _Float16* __restrict__ Gf,   // [B*S][1024] f16 (raw g)
    const _Float16* __restrict__ Kp,   // [B*S][1024] f16
    const _Float16* __restrict__ VT,   // [bh][64][2048] f16
    float* __restrict__ out)           // [B*S][1024] fp32
{
  __shared__ _Float16 Ks[2][64*64];    // K tile [n][d], swizzled, dbuf (16KB)
  __shared__ _Float16 Vts[64*64];      // V^T tile [d][n], swizzled (8KB)
  __shared__ _Float16 Pss[4][16*72];   // per-wave P [m][n], stride 72 (9KB)
  const int t = threadIdx.x;
  const int lane = t & 63, w = t >> 6;
  const int lm = lane & 15, quad = lane >> 4;
  const int bh = blockIdx.y;
  const int b = bh >> 4, h = bh & 15;
  const int qb = blockIdx.x * 64 + w * 16;   // this wave's first Q row
  const size_t kbase = (size_t)b * PS * PD + (size_t)h * PHD;
  const size_t vtb = (size_t)bh * 64 * 2048;

  // staging: lane covers row (w*8 + lane>>3), fetches global block
  // (lane&7)^(lane>>3) so LDS block (lane&7) holds swizzled data
  const int lrow = lane >> 3;
  const int lcb  = ((lane & 7) ^ lrow) * 8;
  // frag-read unswizzle: row&7 = lm&7; original blocks quad and quad+4
  const int kblk0 = ((quad     ^ (lm&7)))*8;
  const int kblk1 = (((quad+4) ^ (lm&7)))*8;

  // Q fragments: rows qb+lm, k = quad*8..+7 (+32); used as B operand.
  // qg = gelu(q*g) * log2e computed here in f32 (q,g rounded to f16 by proj)
  half8 qgf[2];
  {
    size_t qrow = kbase + (size_t)(qb + lm) * PD;
    half8 q0 = *reinterpret_cast<const half8*>(&Qf[qrow + quad*8]);
    half8 q1 = *reinterpret_cast<const half8*>(&Qf[qrow + 32 + quad*8]);
    half8 g0 = *reinterpret_cast<const half8*>(&Gf[qrow + quad*8]);
    half8 g1 = *reinterpret_cast<const half8*>(&Gf[qrow + 32 + quad*8]);
    #pragma unroll
    for (int e=0;e<8;e++) {
      float x0 = (float)q0[e] * (float)g0[e];
      float x1 = (float)q1[e] * (float)g1[e];
      float y0 = 0.5f * x0 * (1.0f + erff(x0 * 0.70710678118f));
      float y1 = 0.5f * x1 * (1.0f + erff(x1 * 0.70710678118f));
      qgf[0][e] = (_Float16)(y0 * 1.44269504f);
      qgf[1][e] = (_Float16)(y1 * 1.44269504f);
    }
  }

  f32x4 o[4];
  #pragma unroll
  for (int dc=0;dc<4;dc++) o[dc] = (f32x4){0.f,0.f,0.f,0.f};
  float lsum = 0.f;   // partial row sum for row m = lm

  const _Float16* kgp = &Kp[kbase + (size_t)(w*8 + lrow)*PD + lcb];
  const _Float16* vgp = &VT[vtb + (size_t)(w*8 + lrow)*2048 + lcb];
  // this lane's LDS slots for the manual V write (same net layout as DMA:
  // LDS block lane&7 of row w*8+lrow holds global block (lane&7)^lrow)
  _Float16* vdst0 = &Vts[((w*8 + lrow)*8 + (lane & 7))*8];
  _Float16* vdst1 = vdst0 + 32*64;

  // QK accumulator C-init: -8*log2(e) => p = 2^s = e^(q.k - 8)
  const f32x4 sinit = {-11.54156036f, -11.54156036f, -11.54156036f, -11.54156036f};

  // prologue: stage tile 0 (K and V both via DMA), then one drain barrier
  ld_g2l_16(kgp,                        &Ks[0][(w*8)*64]);
  ld_g2l_16(kgp + (size_t)32*PD,        &Ks[0][(32 + w*8)*64]);
  ld_g2l_16(vgp,                        &Vts[(w*8)*64]);
  ld_g2l_16(vgp + (size_t)32*2048,      &Vts[(32 + w*8)*64]);
  __syncthreads();

  for (int kt = 0; kt < PS; kt += 64) {
    const int buf = (kt >> 6) & 1;
    const bool nx = (kt + 64) < PS;
    float4 vr0, vr1;
    if (nx) {
      // prefetch next K tile straight to LDS (buf^1 retired one full
      // barrier-pair ago) and next V tile to registers
      ld_g2l_16(kgp + (size_t)(kt+64)*PD, &Ks[buf^1][(w*8)*64]);
      ld_g2l_16(kgp + (size_t)(kt+96)*PD, &Ks[buf^1][(32 + w*8)*64]);
      vr0 = *reinterpret_cast<const float4*>(vgp + kt + 64);
      vr1 = *reinterpret_cast<const float4*>(vgp + (size_t)32*2048 + kt + 64);
    }

    // S^T = K @ QG^T : lane holds (n = ns*16 + quad*4 + r, m = lm)
    f32x4 s[4];
    __builtin_amdgcn_s_setprio(1);
    #pragma unroll
    for (int ns=0; ns<4; ns++) {
      const int rb = (ns*16 + lm)*64;
      half8 kf0 = *reinterpret_cast<const half8*>(&Ks[buf][rb + kblk0]);
      half8 kf1 = *reinterpret_cast<const half8*>(&Ks[buf][rb + kblk1]);
      f32x4 a = sinit;
      a = __builtin_amdgcn_mfma_f32_16x16x32_f16(kf0, qgf[0], a, 0,0,0);
      a = __builtin_amdgcn_mfma_f32_16x16x32_f16(kf1, qgf[1], a, 0,0,0);
      s[ns] = a;
    }
    __builtin_amdgcn_s_setprio(0);

    // p = clamp(2^s); pack 4 consecutive-n f16 -> one b64 store per ns
    #pragma unroll
    for (int ns=0; ns<4; ns++) {
      float p0 = fminf(__builtin_amdgcn_exp2f(s[ns][0]), 60000.0f);
      float p1 = fminf(__builtin_amdgcn_exp2f(s[ns][1]), 60000.0f);
      float p2 = fminf(__builtin_amdgcn_exp2f(s[ns][2]), 60000.0f);
      float p3 = fminf(__builtin_amdgcn_exp2f(s[ns][3]), 60000.0f);
      lsum += (p0+p1) + (p2+p3);
      union { struct { fp16x2 a, b; } s2; half4v v; } u;
      u.s2.a = __builtin_amdgcn_cvt_pkrtz(p0, p1);
      u.s2.b = __builtin_amdgcn_cvt_pkrtz(p2, p3);
      *reinterpret_cast<half4v*>(&Pss[w][lm*72 + ns*16 + quad*4]) = u.v;
    }
    // per-wave LDS: compiler inserts lgkmcnt before readback; no barrier

    // O += P @ V (A = P[m][n] from LDS, B = V^T rows, swizzled blocks)
    half8 pa0 = *reinterpret_cast<const half8*>(&Pss[w][lm*72 + quad*8]);
    half8 pa1 = *reinterpret_cast<const half8*>(&Pss[w][lm*72 + 32 + quad*8]);
    __builtin_amdgcn_s_setprio(1);
    #pragma unroll
    for (int dc=0;dc<4;dc++) {
      const int vb = (dc*16 + lm)*64;
      half8 vb0 = *reinterpret_cast<const half8*>(&Vts[vb + kblk0]);
      half8 vb1 = *reinterpret_cast<const half8*>(&Vts[vb + kblk1]);
      o[dc] = __builtin_amdgcn_mfma_f32_16x16x32_f16(pa0, vb0, o[dc], 0,0,0);
      o[dc] = __builtin_amdgcn_mfma_f32_16x16x32_f16(pa1, vb1, o[dc], 0,0,0);
    }
    __builtin_amdgcn_s_setprio(0);

    // barrier 1: all waves done reading Vts(t) + drains this wave's K-DMA
    // (issued a full compute phase ago) and vr loads
    __syncthreads();
    if (nx) {
      *reinterpret_cast<float4*>(vdst0) = vr0;
      *reinterpret_cast<float4*>(vdst1) = vr1;
    }
    // barrier 2: Vts(t+1) visible to all waves (orders the cheap ds_writes)
    __syncthreads();
  }

  // epilogue: reduce lsum across quads (same lm), fetch 1/l per written row
  float l = lsum;
  l += __shfl_xor(l, 16);
  l += __shfl_xor(l, 32);
  float inv = 1.0f / l;          // valid for row m = lm on every lane
  #pragma unroll
  for (int r=0;r<4;r++) {
    int m = quad*4 + r;
    float invr = __shfl(inv, m); // pull from lane m (quad 0, lm=m)
    int row = qb + m;
    size_t ob = kbase + (size_t)row * PD;
    #pragma unroll
    for (int dc=0;dc<4;dc++) {
      out[ob + dc*16 + lm] = o[dc][r] * invr;
    }
  }
}

extern "C" void kernel_launch(void* const* d_in, const int* in_sizes, int n_in,
                              void* d_out, int out_size, void* d_ws, size_t ws_size,
                              hipStream_t stream) {
  const float* x  = (const float*)d_in[0];
  const float* Wq = (const float*)d_in[1];
  const float* bq = (const float*)d_in[2];
  const float* Wk = (const float*)d_in[3];
  const float* bk = (const float*)d_in[4];
  const float* Wv = (const float*)d_in[5];
  const float* bv = (const float*)d_in[6];
  const float* Wg = (const float*)d_in[7];
  const float* bg = (const float*)d_in[8];
  float* out = (float*)d_out;

  char* ws = (char*)d_ws;
  const size_t MB = 1u << 20;
  // layout (MiB): 0 xh(8), 8 wh(8), 16 qf(8), 24 gf(8), 32 kf(8), 40 vT(8) = 48
  _Float16* xh = (_Float16*)(ws + 0*MB);
  _Float16* wh = (_Float16*)(ws + 8*MB);
  _Float16* qf = (_Float16*)(ws + 16*MB);
  _Float16* gf = (_Float16*)(ws + 24*MB);
  _Float16* kf = (_Float16*)(ws + 32*MB);
  _Float16* vT = (_Float16*)(ws + 40*MB);

  convert_all<<<dim3(2048, 2), 256, 0, stream>>>(x, Wq, Wk, Wv, Wg, xh, wh);

  proj_gemm<<<dim3(PM/128, PD/128, 4), 256, 0, stream>>>(
      xh, wh, bq, bg, bk, bv, qf, gf, kf, vT);

  flash_attn<<<dim3(PS/64, PB*PH), 256, 0, stream>>>(qf, gf, kf, vT, out);
}

// Round 4
// 183.747 us; speedup vs baseline: 1.0782x; 1.0603x over previous
//
#include <hip/hip_runtime.h>
#include <hip/hip_bf16.h>
#include <stdint.h>

// Problem constants
#define PB 2
#define PS 2048
#define PD 1024
#define PH 16
#define PHD 64
#define PM (PB*PS)   // 4096 rows

typedef _Float16 half8 __attribute__((ext_vector_type(8)));
typedef _Float16 half4v __attribute__((ext_vector_type(4)));
typedef __fp16   fp16x2 __attribute__((ext_vector_type(2)));
typedef float    f32x4 __attribute__((ext_vector_type(4)));

// async global->LDS, 16B per lane; LDS dst is wave-uniform base + lane*16.
// LESSON (R10): never feed MFMA fragments straight from global — the lane->
// address map is strided/scattered (16 cache lines per load) and VMEM dies.
// Stage coalesced into LDS; use XOR block swizzle (not padding) so the
// lane-linear DMA layout still gives conflict-free fragment reads.
__device__ __forceinline__ void ld_g2l_16(const void* g, void* l) {
  __builtin_amdgcn_global_load_lds(
      (const __attribute__((address_space(1))) unsigned int*)g,
      (__attribute__((address_space(3))) unsigned int*)l, 16, 0, 0);
}

// ------------- fp32 -> fp16 convert, x and all 4 weights, one launch ------
// y=0: x (4.19M elems = 524288 half8); y=1: four 1M-elem weights -> wh slots
// q(0), k(1), v(2), g(3).
__global__ void convert_all(const float* __restrict__ x,
                            const float* __restrict__ w0, const float* __restrict__ w1,
                            const float* __restrict__ w2, const float* __restrict__ w3,
                            _Float16* __restrict__ xh, _Float16* __restrict__ wh) {
  int i = blockIdx.x * blockDim.x + threadIdx.x;
  const float* src;
  _Float16* dst;
  int idx;
  if (blockIdx.y == 0) {
    src = x; dst = xh; idx = i;
  } else {
    int wsel = i >> 17;            // 131072 half8 per weight
    idx = i & 131071;
    src = (wsel==0)?w0:(wsel==1)?w1:(wsel==2)?w2:w3;
    dst = wh + (size_t)wsel * 1048576;
  }
  float4 f0 = reinterpret_cast<const float4*>(src)[2*idx];
  float4 f1 = reinterpret_cast<const float4*>(src)[2*idx+1];
  half8 o;
  o[0]=(_Float16)f0.x; o[1]=(_Float16)f0.y; o[2]=(_Float16)f0.z; o[3]=(_Float16)f0.w;
  o[4]=(_Float16)f1.x; o[5]=(_Float16)f1.y; o[6]=(_Float16)f1.z; o[7]=(_Float16)f1.w;
  reinterpret_cast<half8*>(dst)[idx] = o;
}

// ------------------ projection GEMM: one weight per block ------------------
// R13: uniform 4-way split (z: 0=q,1=g,2=k,3=v), 128x128 tile, 1024 blocks.
// Single acc[4][4] (~115 regs) + 32KB LDS + __launch_bounds__(256,3) ->
// 3 blocks/CU resident, m97-regime wave-level latency hiding.
// gelu(q*g) moved to flash's Q-load (q,g stored raw f16).
// z==3 (v): epilogue LDS-transpose (reuse staging LDS) -> coalesced half8
// vT stores (the old per-element scatter had 2x write amplification).
// LDS XOR swizzle: row r stores 16B-block b at b^((r>>1)&3).
__global__ __launch_bounds__(256, 3) void proj_gemm(
    const _Float16* __restrict__ xh, const _Float16* __restrict__ wh,
    const float* __restrict__ bqp, const float* __restrict__ bgp,
    const float* __restrict__ bkp, const float* __restrict__ bvp,
    _Float16* __restrict__ qf, _Float16* __restrict__ gf,
    _Float16* __restrict__ kf, _Float16* __restrict__ vT)
{
  const int K = 1024;
  __shared__ _Float16 Sm[16384];   // 32KB: A dbuf [0:8192), B dbuf [8192:16384)
  const int z = blockIdx.z;
  const int wslot = (z==0)?0:(z==1)?3:(z==2)?1:2;   // wh order q,k,v,g
  const size_t woff = (size_t)wslot * (1024*1024);
  const float* bias = (z==0)?bqp:(z==1)?bgp:(z==2)?bkp:bvp;
  _Float16* outp = (z==0)?qf:(z==1)?gf:kf;          // z==3 handled separately
  const int m0 = blockIdx.x * 128;
  const int n0 = blockIdx.y * 128;
  const int t = threadIdx.x;
  const int lane = t & 63;
  const int w = t >> 6;
  const int wr = w >> 1, wc = w & 1;
  const int lm = lane & 15, quad = lane >> 4;
  // staging swizzle: lane covers row lin>>2, stores LDS block lane&3; fetch
  // global block (lane&3)^key, key = (row>>1)&3 = (lane>>3)&3
  const int scb = (((lane&3) ^ ((lane>>3)&3)))*8;
  // frag-read unswizzle key (row = ..*16 + lm -> (row>>1)&3 = (lm>>1)&3)
  const int rblk = ((quad ^ ((lm>>1)&3)))*8;

  auto stage = [&](int buf, int k0) {
    #pragma unroll
    for (int c=0;c<2;c++) {
      int lin = c*256 + t;
      int row = lin >> 2;
      size_t ga = (size_t)(m0+row)*K + k0 + scb;
      size_t gb = (size_t)(n0+row)*K + k0 + scb;
      int lo8 = (c*256 + w*64)*8;     // wave-uniform LDS chunk base (elems)
      ld_g2l_16(&xh[ga],        &Sm[buf*4096 + lo8]);
      ld_g2l_16(&wh[woff + gb], &Sm[8192 + buf*4096 + lo8]);
    }
  };

  f32x4 acc[4][4];
  #pragma unroll
  for (int i=0;i<4;i++)
    #pragma unroll
    for (int j=0;j<4;j++) acc[i][j] = (f32x4){0.f,0.f,0.f,0.f};

  stage(0, 0);
  __syncthreads();

  for (int k0 = 0; k0 < K; k0 += 32) {
    const int cur = (k0 >> 5) & 1;
    if (k0 + 32 < K) stage(cur ^ 1, k0 + 32);   // prefetch under MFMAs

    half8 ah[4];
    #pragma unroll
    for (int i=0;i<4;i++)
      ah[i] = *reinterpret_cast<const half8*>(&Sm[cur*4096 + (wr*64 + i*16 + lm)*32 + rblk]);
    #pragma unroll
    for (int j=0;j<4;j++) {
      half8 b = *reinterpret_cast<const half8*>(&Sm[8192 + cur*4096 + (wc*64 + j*16 + lm)*32 + rblk]);
      #pragma unroll
      for (int i=0;i<4;i++)
        acc[i][j] = __builtin_amdgcn_mfma_f32_16x16x32_f16(ah[i], b, acc[i][j], 0,0,0);
    }
    // single barrier/K-step: drains next-tile DMA (issued a full MFMA phase
    // ago) and retires all waves' reads of buf cur.
    __syncthreads();
  }

  // epilogue. C layout: col=lane&15, row=quad*4+reg
  if (z < 3) {
    #pragma unroll
    for (int j=0;j<4;j++) {
      int n = n0 + wc*64 + j*16 + lm;
      float bn = bias[n];
      #pragma unroll
      for (int i=0;i<4;i++) {
        int mb = m0 + wr*64 + i*16 + quad*4;
        #pragma unroll
        for (int r=0;r<4;r++)
          outp[(size_t)(mb+r)*PD + n] = (_Float16)(acc[i][j][r] + bn);
      }
    }
  } else {
    // v: transpose 128(token) x 128(n) tile through LDS, store coalesced.
    // Sm row = n_local (128 tokens/row); token-chunk c (8 elems) stored at
    // chunk position c ^ (n_local&15)  -> both sides swizzled, banks spread.
    #pragma unroll
    for (int j=0;j<4;j++) {
      int nl = wc*64 + j*16 + lm;
      float bn = bias[n0 + nl];
      #pragma unroll
      for (int i=0;i<4;i++) {
        int tb = wr*64 + i*16 + quad*4;   // token base, 8B-aligned in chunk
        half4v pv;
        #pragma unroll
        for (int r=0;r<4;r++) pv[r] = (_Float16)(acc[i][j][r] + bn);
        int sw = (tb >> 3) ^ (nl & 15);
        *reinterpret_cast<half4v*>(&Sm[nl*128 + sw*8 + (tb & 7)]) = pv;
      }
    }
    __syncthreads();
    // copy out: thread t -> vT row nl2 = t>>1, token-half (t&1)*64.
    // vT[bh][d][s]: contiguous along s -> half8 stores, fully coalesced.
    const int nl2 = t >> 1, co = (t & 1) * 8;
    const int hh = (n0 + nl2) >> 6, dd = (n0 + nl2) & 63;
    const int bb2 = m0 >> 11;
    const size_t vbase = ((size_t)((bb2*16 + hh)*64 + dd))*2048 + (m0 & 2047);
    #pragma unroll
    for (int c=0;c<8;c++) {
      int cc = co + c;
      half8 vv = *reinterpret_cast<const half8*>(&Sm[nl2*128 + ((cc ^ (nl2&15))<<3)]);
      *reinterpret_cast<half8*>(&vT[vbase + cc*8]) = vv;
    }
  }
}

// ---------------- flash attention v12 (8-wave, ones-MFMA lsum) -------------
// R14: grid (S/128, B*H) = 512 blocks x 8 waves (was 1024 x 4). Per-wave
// work identical (16 Q rows); block now shares each K/V tile across 128 Q
// rows: 2 blocks/CU x 8 waves = 16 waves/CU (occupancy 36%->~50%), K/V DMA
// per Q-row halved, one global_load_lds per tensor per wave.
// lsum via ones-MFMA: l = P @ 1 accumulated on the idle matrix pipe
// (o4[r] = l for Q-row quad*4+r, in-lane); kills 12 VALU adds/tile, the
// serial lsum chain, and the epilogue shuffle-reduce; denominator is
// numerically consistent with the f16 P used by PV.
// K double-buffered via global_load_lds; V pipelined via reg-staging.
// softmax: p = exp2(s) with C-init = -8*log2e (qg pre-scaled by log2e at
// Q-load). setprio(1) around MFMA clusters (T5).
__global__ __launch_bounds__(512) void flash_attn(
    const _Float16* __restrict__ Qf,   // [B*S][1024] f16 (raw q)
    const _Float16* __restrict__ Gf,   // [B*S][1024] f16 (raw g)
    const _Float16* __restrict__ Kp,   // [B*S][1024] f16
    const _Float16* __restrict__ VT,   // [bh][64][2048] f16
    float* __restrict__ out)           // [B*S][1024] fp32
{
  __shared__ _Float16 Ks[2][64*64];    // K tile [n][d], swizzled, dbuf (16KB)
  __shared__ _Float16 Vts[64*64];      // V^T tile [d][n], swizzled (8KB)
  __shared__ _Float16 Pss[8][16*72];   // per-wave P [m][n], stride 72 (18KB)
  const int t = threadIdx.x;
  const int lane = t & 63, w = t >> 6;
  const int lm = lane & 15, quad = lane >> 4;
  const int bh = blockIdx.y;
  const int b = bh >> 4, h = bh & 15;
  const int qb = blockIdx.x * 128 + w * 16;  // this wave's first Q row
  const size_t kbase = (size_t)b * PS * PD + (size_t)h * PHD;
  const size_t vtb = (size_t)bh * 64 * 2048;

  // staging: wave w covers rows w*8 + (lane>>3) -> 8 waves cover all 64
  // rows in ONE call per tensor. Lane fetches global block
  // (lane&7)^(lane>>3) so LDS block (lane&7) holds swizzled data.
  const int lrow = lane >> 3;
  const int lcb  = ((lane & 7) ^ lrow) * 8;
  // frag-read unswizzle: row&7 = lm&7; original blocks quad and quad+4
  const int kblk0 = ((quad     ^ (lm&7)))*8;
  const int kblk1 = (((quad+4) ^ (lm&7)))*8;

  // Q fragments: rows qb+lm, k = quad*8..+7 (+32); used as B operand.
  // qg = gelu(q*g) * log2e computed here in f32 (q,g rounded to f16 by proj)
  half8 qgf[2];
  {
    size_t qrow = kbase + (size_t)(qb + lm) * PD;
    half8 q0 = *reinterpret_cast<const half8*>(&Qf[qrow + quad*8]);
    half8 q1 = *reinterpret_cast<const half8*>(&Qf[qrow + 32 + quad*8]);
    half8 g0 = *reinterpret_cast<const half8*>(&Gf[qrow + quad*8]);
    half8 g1 = *reinterpret_cast<const half8*>(&Gf[qrow + 32 + quad*8]);
    #pragma unroll
    for (int e=0;e<8;e++) {
      float x0 = (float)q0[e] * (float)g0[e];
      float x1 = (float)q1[e] * (float)g1[e];
      float y0 = 0.5f * x0 * (1.0f + erff(x0 * 0.70710678118f));
      float y1 = 0.5f * x1 * (1.0f + erff(x1 * 0.70710678118f));
      qgf[0][e] = (_Float16)(y0 * 1.44269504f);
      qgf[1][e] = (_Float16)(y1 * 1.44269504f);
    }
  }

  // ones fragment for the row-sum MFMA (B operand, all 1.0h)
  half8 ones;
  #pragma unroll
  for (int e=0;e<8;e++) ones[e] = (_Float16)1.0f;

  f32x4 o[4];
  #pragma unroll
  for (int dc=0;dc<4;dc++) o[dc] = (f32x4){0.f,0.f,0.f,0.f};
  f32x4 o4 = (f32x4){0.f,0.f,0.f,0.f};   // row sums l (per Q-row quad*4+r)

  const _Float16* kgp = &Kp[kbase + (size_t)(w*8 + lrow)*PD + lcb];
  const _Float16* vgp = &VT[vtb + (size_t)(w*8 + lrow)*2048 + lcb];
  // this lane's LDS slot for the manual V write (same net layout as DMA:
  // LDS block lane&7 of row w*8+lrow holds global block (lane&7)^lrow)
  _Float16* vdst0 = &Vts[((w*8 + lrow)*8 + (lane & 7))*8];

  // QK accumulator C-init: -8*log2(e) => p = 2^s = e^(q.k - 8)
  const f32x4 sinit = {-11.54156036f, -11.54156036f, -11.54156036f, -11.54156036f};

  // prologue: stage tile 0 (K and V both via DMA), then one drain barrier
  ld_g2l_16(kgp, &Ks[0][(w*8)*64]);
  ld_g2l_16(vgp, &Vts[(w*8)*64]);
  __syncthreads();

  for (int kt = 0; kt < PS; kt += 64) {
    const int buf = (kt >> 6) & 1;
    const bool nx = (kt + 64) < PS;
    float4 vr0;
    if (nx) {
      // prefetch next K tile straight to LDS (buf^1 retired one full
      // barrier-pair ago) and next V tile to registers
      ld_g2l_16(kgp + (size_t)(kt+64)*PD, &Ks[buf^1][(w*8)*64]);
      vr0 = *reinterpret_cast<const float4*>(vgp + kt + 64);
    }

    // S^T = K @ QG^T : lane holds (n = ns*16 + quad*4 + r, m = lm)
    f32x4 s[4];
    __builtin_amdgcn_s_setprio(1);
    #pragma unroll
    for (int ns=0; ns<4; ns++) {
      const int rb = (ns*16 + lm)*64;
      half8 kf0 = *reinterpret_cast<const half8*>(&Ks[buf][rb + kblk0]);
      half8 kf1 = *reinterpret_cast<const half8*>(&Ks[buf][rb + kblk1]);
      f32x4 a = sinit;
      a = __builtin_amdgcn_mfma_f32_16x16x32_f16(kf0, qgf[0], a, 0,0,0);
      a = __builtin_amdgcn_mfma_f32_16x16x32_f16(kf1, qgf[1], a, 0,0,0);
      s[ns] = a;
    }
    __builtin_amdgcn_s_setprio(0);

    // p = clamp(2^s); pack 4 consecutive-n f16 -> one b64 store per ns
    #pragma unroll
    for (int ns=0; ns<4; ns++) {
      float p0 = fminf(__builtin_amdgcn_exp2f(s[ns][0]), 60000.0f);
      float p1 = fminf(__builtin_amdgcn_exp2f(s[ns][1]), 60000.0f);
      float p2 = fminf(__builtin_amdgcn_exp2f(s[ns][2]), 60000.0f);
      float p3 = fminf(__builtin_amdgcn_exp2f(s[ns][3]), 60000.0f);
      union { struct { fp16x2 a, b; } s2; half4v v; } u;
      u.s2.a = __builtin_amdgcn_cvt_pkrtz(p0, p1);
      u.s2.b = __builtin_amdgcn_cvt_pkrtz(p2, p3);
      *reinterpret_cast<half4v*>(&Pss[w][lm*72 + ns*16 + quad*4]) = u.v;
    }
    // per-wave LDS: compiler inserts lgkmcnt before readback; no barrier

    // O += P @ V (A = P[m][n] from LDS, B = V^T rows, swizzled blocks);
    // l += P @ 1 on the same pipe (ones B-fragment, no LDS read)
    half8 pa0 = *reinterpret_cast<const half8*>(&Pss[w][lm*72 + quad*8]);
    half8 pa1 = *reinterpret_cast<const half8*>(&Pss[w][lm*72 + 32 + quad*8]);
    __builtin_amdgcn_s_setprio(1);
    #pragma unroll
    for (int dc=0;dc<4;dc++) {
      const int vb = (dc*16 + lm)*64;
      half8 vb0 = *reinterpret_cast<const half8*>(&Vts[vb + kblk0]);
      half8 vb1 = *reinterpret_cast<const half8*>(&Vts[vb + kblk1]);
      o[dc] = __builtin_amdgcn_mfma_f32_16x16x32_f16(pa0, vb0, o[dc], 0,0,0);
      o[dc] = __builtin_amdgcn_mfma_f32_16x16x32_f16(pa1, vb1, o[dc], 0,0,0);
    }
    o4 = __builtin_amdgcn_mfma_f32_16x16x32_f16(pa0, ones, o4, 0,0,0);
    o4 = __builtin_amdgcn_mfma_f32_16x16x32_f16(pa1, ones, o4, 0,0,0);
    __builtin_amdgcn_s_setprio(0);

    // barrier 1: all waves done reading Vts(t) + drains this wave's K-DMA
    // (issued a full compute phase ago) and vr loads
    __syncthreads();
    if (nx) {
      *reinterpret_cast<float4*>(vdst0) = vr0;
    }
    // barrier 2: Vts(t+1) visible to all waves (orders the cheap ds_writes)
    __syncthreads();
  }

  // epilogue: o4[r] = l for Q-row quad*4+r (identical across lm) — no
  // cross-lane reduce needed.
  #pragma unroll
  for (int r=0;r<4;r++) {
    float invr = 1.0f / o4[r];
    int row = qb + quad*4 + r;
    size_t ob = kbase + (size_t)row * PD;
    #pragma unroll
    for (int dc=0;dc<4;dc++) {
      out[ob + dc*16 + lm] = o[dc][r] * invr;
    }
  }
}

extern "C" void kernel_launch(void* const* d_in, const int* in_sizes, int n_in,
                              void* d_out, int out_size, void* d_ws, size_t ws_size,
                              hipStream_t stream) {
  const float* x  = (const float*)d_in[0];
  const float* Wq = (const float*)d_in[1];
  const float* bq = (const float*)d_in[2];
  const float* Wk = (const float*)d_in[3];
  const float* bk = (const float*)d_in[4];
  const float* Wv = (const float*)d_in[5];
  const float* bv = (const float*)d_in[6];
  const float* Wg = (const float*)d_in[7];
  const float* bg = (const float*)d_in[8];
  float* out = (float*)d_out;

  char* ws = (char*)d_ws;
  const size_t MB = 1u << 20;
  // layout (MiB): 0 xh(8), 8 wh(8), 16 qf(8), 24 gf(8), 32 kf(8), 40 vT(8) = 48
  _Float16* xh = (_Float16*)(ws + 0*MB);
  _Float16* wh = (_Float16*)(ws + 8*MB);
  _Float16* qf = (_Float16*)(ws + 16*MB);
  _Float16* gf = (_Float16*)(ws + 24*MB);
  _Float16* kf = (_Float16*)(ws + 32*MB);
  _Float16* vT = (_Float16*)(ws + 40*MB);

  convert_all<<<dim3(2048, 2), 256, 0, stream>>>(x, Wq, Wk, Wv, Wg, xh, wh);

  proj_gemm<<<dim3(PM/128, PD/128, 4), 256, 0, stream>>>(
      xh, wh, bq, bg, bk, bv, qf, gf, kf, vT);

  flash_attn<<<dim3(PS/128, PB*PH), 512, 0, stream>>>(qf, gf, kf, vT, out);
}